// Round 2
// baseline (766.790 us; speedup 1.0000x reference)
//
#include <hip/hip_runtime.h>
#include <hip/hip_bf16.h>
#include <math.h>

#define V     8000
#define D_    300
#define B_    128
#define L_    300
#define C_    54
#define CHUNK 20            // 300 = 15 * 20, no partial chunks
#define STR   21            // padded LDS row stride
#define NELEM (L_ * CHUNK)  // 6000
#define KPT   24            // ceil(6000 / 256)

// ---------------- Kernel 1: gather edge weights ----------------
// one thread per (b,l); 7 independent random loads in flight (MLP)
// w_ws layout: [B][L][8] (o padded 7->8, 32B aligned per (b,l))
__global__ __launch_bounds__(128) void wgather_kernel(
    const float* __restrict__ edge_w,
    const int*   __restrict__ docs,
    const int*   __restrict__ edges_matrix,
    float* __restrict__ w_ws)
{
    int idx = blockIdx.x * 128 + threadIdx.x;
    if (idx >= B_ * L_) return;
    int b = idx / L_;
    int l = idx - b * L_;
    const int* drow = docs + b * L_;
    int d1 = drow[l];
    size_t base = (size_t)d1 * V;

    int d2[7];
    #pragma unroll
    for (int o = 0; o < 7; ++o) {
        int nb = min(max(l + o - 3, 0), L_ - 1);
        d2[o] = drow[nb];
    }
    int eid[7];
    #pragma unroll
    for (int o = 0; o < 7; ++o) eid[o] = edges_matrix[base + d2[o]];
    float w[7];
    #pragma unroll
    for (int o = 0; o < 7; ++o) w[o] = edge_w[eid[o]];

    float4* dst = (float4*)(w_ws + (size_t)idx * 8);
    dst[0] = make_float4(w[0], w[1], w[2], w[3]);
    dst[1] = make_float4(w[4], w[5], w[6], 0.f);
}

// ---------------- Kernel 2: h0 gather + T=2 propagation + pooled sum ----------------
// grid: (15, B), block: 256; single LDS h-buffer, register-staged update
__global__ __launch_bounds__(256, 4) void prop_kernel(
    const float* __restrict__ node_embed,
    const float* __restrict__ node_eta,
    const float* __restrict__ w_ws,
    const int*   __restrict__ docs,
    float* __restrict__ pooled)   // [B][D]
{
    int b   = blockIdx.y;
    int d0  = blockIdx.x * CHUNK;
    int tid = threadIdx.x;

    __shared__ float h_s[L_ * STR];   // 300*21*4 = 25200 B
    __shared__ float w_s[L_ * 8];     //  9600 B
    __shared__ float eta_s[L_];       //  1200 B
    __shared__ int   docs_s[L_];      //  1200 B
    __shared__ float red[12 * 20];    //   960 B   -> total ~38.2 KB => 4 blocks/CU

    for (int l = tid; l < L_; l += 256) {
        int dc = docs[b * L_ + l];
        docs_s[l] = dc;
        eta_s[l]  = node_eta[dc];
    }
    for (int i = tid; i < L_ * 8; i += 256)
        w_s[i] = w_ws[b * (L_ * 8) + i];
    __syncthreads();

    // precompute per-thread indices + load h0
    int lk[KPT], ak[KPT];
    #pragma unroll
    for (int k = 0; k < KPT; ++k) {
        int e = tid + k * 256;
        if (e < NELEM) {
            int l  = e / CHUNK;
            int dd = e - l * CHUNK;
            lk[k] = l;
            ak[k] = l * STR + dd;
            h_s[ak[k]] = node_embed[(size_t)docs_s[l] * D_ + d0 + dd];
        } else { lk[k] = 0; ak[k] = 0; }
    }
    __syncthreads();

    for (int step = 0; step < 2; ++step) {
        float nv[KPT];
        #pragma unroll
        for (int k = 0; k < KPT; ++k) {
            int e = tid + k * 256;
            if (e < NELEM) {
                int l = lk[k];
                int a = ak[k];
                float own = h_s[a];
                float msg = -3.402823466e38f;
                #pragma unroll
                for (int o = 0; o < 7; ++o) {
                    int nb = l + o - 3;
                    if ((unsigned)nb < (unsigned)L_) {
                        float hv = (o == 3) ? own : h_s[a + (o - 3) * STR];
                        msg = fmaxf(msg, w_s[l * 8 + o] * hv);
                    }
                }
                float et = eta_s[l];
                nv[k] = et * own + (1.f - et) * msg;
            }
        }
        __syncthreads();
        #pragma unroll
        for (int k = 0; k < KPT; ++k) {
            int e = tid + k * 256;
            if (e < NELEM) h_s[ak[k]] = nv[k];
        }
        __syncthreads();
    }

    // pooled[b, d0+dd] = sum_l h[l][dd]
    int grp = tid / CHUNK;          // 12 groups of 20 active (tid < 240)
    int dd  = tid - grp * CHUNK;
    if (grp < 12) {
        float s = 0.f;
        for (int l = grp; l < L_; l += 12)
            s += h_s[l * STR + dd];
        red[grp * CHUNK + dd] = s;
    }
    __syncthreads();
    if (tid < CHUNK) {
        float s = 0.f;
        #pragma unroll
        for (int g = 0; g < 12; ++g) s += red[g * CHUNK + tid];
        pooled[b * D_ + d0 + tid] = s;
    }
}

// ---------------- Kernel 3: relu + batchnorm over batch axis ----------------
__global__ __launch_bounds__(128) void bn_kernel(
    const float* __restrict__ pooled,
    const float* __restrict__ gamma,
    const float* __restrict__ beta,
    float* __restrict__ xn)
{
    int d = blockIdx.x;
    int b = threadIdx.x;
    float x = fmaxf(pooled[b * D_ + d], 0.f);

    float v1 = x, v2 = x * x;
    #pragma unroll
    for (int off = 32; off > 0; off >>= 1) {
        v1 += __shfl_down(v1, off, 64);
        v2 += __shfl_down(v2, off, 64);
    }
    __shared__ float s1[2], s2[2];
    int lane = b & 63, wv = b >> 6;
    if (lane == 0) { s1[wv] = v1; s2[wv] = v2; }
    __syncthreads();
    float mean = (s1[0] + s1[1]) * (1.f / 128.f);
    float var  = (s2[0] + s2[1]) * (1.f / 128.f) - mean * mean;
    float xh = (x - mean) / sqrtf(var + 1e-5f);
    xn[b * D_ + d] = xh * gamma[d] + beta[d];
}

// ---------------- Kernel 4: matmul + bias + sigmoid ----------------
__global__ __launch_bounds__(64) void out_kernel(
    const float* __restrict__ xn,
    const float* __restrict__ Wm,
    const float* __restrict__ bias,
    float* __restrict__ out)
{
    int b = blockIdx.x;
    int c = threadIdx.x;
    if (c >= C_) return;
    float acc = bias[c];
    for (int k = 0; k < D_; ++k)
        acc = fmaf(xn[b * D_ + k], Wm[k * C_ + c], acc);
    out[b * C_ + c] = 1.f / (1.f + expf(-acc));
}

extern "C" void kernel_launch(void* const* d_in, const int* in_sizes, int n_in,
                              void* d_out, int out_size, void* d_ws, size_t ws_size,
                              hipStream_t stream) {
    const float* node_embed   = (const float*)d_in[0];
    const float* node_eta     = (const float*)d_in[1];
    const float* edge_w       = (const float*)d_in[2];
    const float* bn_gamma     = (const float*)d_in[3];
    const float* bn_beta      = (const float*)d_in[4];
    const float* Wm           = (const float*)d_in[5];
    const float* bias         = (const float*)d_in[6];
    const int*   docs         = (const int*)d_in[7];
    const int*   edges_matrix = (const int*)d_in[8];
    float* out = (float*)d_out;

    // workspace layout
    float* w_ws   = (float*)d_ws;                       // B*L*8 floats
    float* pooled = w_ws + (size_t)B_ * L_ * 8;         // B*D floats
    float* xn     = pooled + (size_t)B_ * D_;           // B*D floats

    // 1. edge-weight gather (one thread per (b,l), 7 loads in flight)
    {
        int total = B_ * L_;
        wgather_kernel<<<(total + 127) / 128, 128, 0, stream>>>(edge_w, docs, edges_matrix, w_ws);
    }
    // 2. propagation
    {
        dim3 grid(D_ / CHUNK, B_);  // (15, 128)
        prop_kernel<<<grid, 256, 0, stream>>>(node_embed, node_eta, w_ws, docs, pooled);
    }
    // 3. batchnorm
    bn_kernel<<<D_, 128, 0, stream>>>(pooled, bn_gamma, bn_beta, xn);
    // 4. output
    out_kernel<<<B_, 64, 0, stream>>>(xn, Wm, bias, out);
}

// Round 3
// 381.576 us; speedup vs baseline: 2.0095x; 2.0095x over previous
//
#include <hip/hip_runtime.h>
#include <hip/hip_bf16.h>
#include <math.h>

#define V     8000
#define D_    300
#define B_    128
#define L_    300
#define C_    54
#define CHUNK 10            // 300 = 30 * 10
#define STR   11            // padded LDS row stride
#define NELEM (L_ * CHUNK)  // 3000
#define KPT   12            // ceil(3000 / 256)

// ---------------- Kernel 1: gather edge weights + eta ----------------
// one thread per (b,l,o) -> max TLP for the random edges_matrix gather
// w_ws layout: [B][L][8] (o padded 7->8); eta_ws: [B][L]
__global__ __launch_bounds__(256) void wgather_kernel(
    const float* __restrict__ edge_w,
    const float* __restrict__ node_eta,
    const int*   __restrict__ docs,
    const int*   __restrict__ edges_matrix,
    float* __restrict__ w_ws,
    float* __restrict__ eta_ws)
{
    int idx = blockIdx.x * 256 + threadIdx.x;
    if (idx >= B_ * L_ * 7) return;
    int b   = idx / (L_ * 7);
    int rem = idx - b * (L_ * 7);
    int l   = rem / 7;
    int o   = rem - l * 7;
    const int* drow = docs + b * L_;
    int d1 = drow[l];
    int nb = min(max(l + o - 3, 0), L_ - 1);
    int d2 = drow[nb];
    int eid = edges_matrix[(size_t)d1 * V + d2];
    w_ws[((size_t)b * L_ + l) * 8 + o] = edge_w[eid];
    if (o == 3) eta_ws[b * L_ + l] = node_eta[d1];
}

// ---------------- Kernel 2: h0 gather + T=2 propagation + pooled sum ----------------
// grid: (30, B), block: 256; single LDS h buffer, nv[12] register staging,
// indices recomputed each phase (no spill-prone index arrays)
__global__ __launch_bounds__(256, 4) void prop_kernel(
    const float* __restrict__ node_embed,
    const float* __restrict__ eta_ws,
    const float* __restrict__ w_ws,
    const int*   __restrict__ docs,
    float* __restrict__ pooled)   // [B][D]
{
    int b   = blockIdx.y;
    int d0  = blockIdx.x * CHUNK;
    int tid = threadIdx.x;

    __shared__ float h_s[L_ * STR];   // 300*11*4 = 13200 B
    __shared__ float w_s[L_ * 8];     //  9600 B
    __shared__ float eta_s[L_];       //  1200 B
    __shared__ int   docs_s[L_];      //  1200 B
    __shared__ float red[25 * CHUNK]; //  1000 B  -> ~26.2 KB total => 6 blocks/CU

    for (int l = tid; l < L_; l += 256) {
        docs_s[l] = docs[b * L_ + l];
        eta_s[l]  = eta_ws[b * L_ + l];
    }
    for (int i = tid; i < L_ * 8; i += 256)
        w_s[i] = w_ws[(size_t)b * (L_ * 8) + i];
    __syncthreads();

    // load h0 chunk
    #pragma unroll
    for (int k = 0; k < KPT; ++k) {
        int e = tid + k * 256;
        if (e < NELEM) {
            int l  = e / CHUNK;
            int dd = e - l * CHUNK;
            h_s[l * STR + dd] = node_embed[(size_t)docs_s[l] * D_ + d0 + dd];
        }
    }
    __syncthreads();

    for (int step = 0; step < 2; ++step) {
        float nv[KPT];
        #pragma unroll
        for (int k = 0; k < KPT; ++k) {
            int e = tid + k * 256;
            if (e < NELEM) {
                int l  = e / CHUNK;
                int dd = e - l * CHUNK;
                int a  = l * STR + dd;
                float own = h_s[a];
                float msg = -3.402823466e38f;
                #pragma unroll
                for (int o = 0; o < 7; ++o) {
                    int nb = l + o - 3;
                    if ((unsigned)nb < (unsigned)L_) {
                        float hv = (o == 3) ? own : h_s[a + (o - 3) * STR];
                        msg = fmaxf(msg, w_s[l * 8 + o] * hv);
                    }
                }
                float et = eta_s[l];
                nv[k] = et * own + (1.f - et) * msg;
            }
        }
        __syncthreads();
        #pragma unroll
        for (int k = 0; k < KPT; ++k) {
            int e = tid + k * 256;
            if (e < NELEM) {
                int l  = e / CHUNK;
                int dd = e - l * CHUNK;
                h_s[l * STR + dd] = nv[k];
            }
        }
        __syncthreads();
    }

    // pooled[b, d0+dd] = sum_l h[l][dd] ; 25 groups x 12 l-values
    int grp = tid / CHUNK;
    int dd  = tid - grp * CHUNK;
    if (grp < 25) {
        float s = 0.f;
        #pragma unroll
        for (int j = 0; j < 12; ++j)
            s += h_s[(grp + j * 25) * STR + dd];
        red[grp * CHUNK + dd] = s;
    }
    __syncthreads();
    if (tid < CHUNK) {
        float s = 0.f;
        #pragma unroll
        for (int g = 0; g < 25; ++g) s += red[g * CHUNK + tid];
        pooled[b * D_ + d0 + tid] = s;
    }
}

// ---------------- Kernel 3: relu + batchnorm over batch axis ----------------
__global__ __launch_bounds__(128) void bn_kernel(
    const float* __restrict__ pooled,
    const float* __restrict__ gamma,
    const float* __restrict__ beta,
    float* __restrict__ xn)
{
    int d = blockIdx.x;
    int b = threadIdx.x;
    float x = fmaxf(pooled[b * D_ + d], 0.f);

    float v1 = x, v2 = x * x;
    #pragma unroll
    for (int off = 32; off > 0; off >>= 1) {
        v1 += __shfl_down(v1, off, 64);
        v2 += __shfl_down(v2, off, 64);
    }
    __shared__ float s1[2], s2[2];
    int lane = b & 63, wv = b >> 6;
    if (lane == 0) { s1[wv] = v1; s2[wv] = v2; }
    __syncthreads();
    float mean = (s1[0] + s1[1]) * (1.f / 128.f);
    float var  = (s2[0] + s2[1]) * (1.f / 128.f) - mean * mean;
    float xh = (x - mean) / sqrtf(var + 1e-5f);
    xn[b * D_ + d] = xh * gamma[d] + beta[d];
}

// ---------------- Kernel 4: matmul + bias + sigmoid ----------------
__global__ __launch_bounds__(64) void out_kernel(
    const float* __restrict__ xn,
    const float* __restrict__ Wm,
    const float* __restrict__ bias,
    float* __restrict__ out)
{
    int b = blockIdx.x;
    int c = threadIdx.x;
    if (c >= C_) return;
    float acc = bias[c];
    for (int k = 0; k < D_; ++k)
        acc = fmaf(xn[b * D_ + k], Wm[k * C_ + c], acc);
    out[b * C_ + c] = 1.f / (1.f + expf(-acc));
}

extern "C" void kernel_launch(void* const* d_in, const int* in_sizes, int n_in,
                              void* d_out, int out_size, void* d_ws, size_t ws_size,
                              hipStream_t stream) {
    const float* node_embed   = (const float*)d_in[0];
    const float* node_eta     = (const float*)d_in[1];
    const float* edge_w       = (const float*)d_in[2];
    const float* bn_gamma     = (const float*)d_in[3];
    const float* bn_beta      = (const float*)d_in[4];
    const float* Wm           = (const float*)d_in[5];
    const float* bias         = (const float*)d_in[6];
    const int*   docs         = (const int*)d_in[7];
    const int*   edges_matrix = (const int*)d_in[8];
    float* out = (float*)d_out;

    // workspace layout
    float* w_ws   = (float*)d_ws;                       // B*L*8
    float* eta_ws = w_ws + (size_t)B_ * L_ * 8;         // B*L
    float* pooled = eta_ws + (size_t)B_ * L_;           // B*D
    float* xn     = pooled + (size_t)B_ * D_;           // B*D

    // 1. edge-weight + eta gather (one thread per edge: max TLP)
    {
        int total = B_ * L_ * 7;
        wgather_kernel<<<(total + 255) / 256, 256, 0, stream>>>(
            edge_w, node_eta, docs, edges_matrix, w_ws, eta_ws);
    }
    // 2. propagation
    {
        dim3 grid(D_ / CHUNK, B_);  // (30, 128)
        prop_kernel<<<grid, 256, 0, stream>>>(node_embed, eta_ws, w_ws, docs, pooled);
    }
    // 3. batchnorm
    bn_kernel<<<D_, 128, 0, stream>>>(pooled, bn_gamma, bn_beta, xn);
    // 4. output
    out_kernel<<<B_, 64, 0, stream>>>(xn, Wm, bias, out);
}